// Round 18
// baseline (1163.538 us; speedup 1.0000x reference)
//
#include <hip/hip_runtime.h>
#include <math.h>

#define NB 1024
#define ND 512
#define ND2 1024
#define NSTEPS 8
#define NSTACK 16
#define NK 1024
#define NV 32000
#define FEPS 1e-6f
#define ATT_SCALE 0.044194173824159216f

typedef _Float16 f16;
typedef f16 f16x8 __attribute__((ext_vector_type(8)));
typedef f16 f16x4 __attribute__((ext_vector_type(4)));
typedef float f32x4 __attribute__((ext_vector_type(4)));
typedef unsigned long long u64;

// LDS layout: row stride 32 halfs (64B), 16B-chunk swizzle (0 conflicts, r7-verified)
__device__ __forceinline__ int swz(int row, int chunk) {
    return row * 32 + ((chunk ^ ((row >> 1) & 3)) * 8);
}

__device__ __forceinline__ void gl16(const f16* g, f16* l) {
    __builtin_amdgcn_global_load_lds(
        (const __attribute__((address_space(1))) void*)g,
        (__attribute__((address_space(3))) void*)l, 16, 0, 0);
}

// ordered-float encode: monotone u32; key = (ord<<32)|idx, global min == (min val, min idx)
__device__ __forceinline__ u64 fkey(float v, int idx) {
    unsigned int ub = __float_as_uint(v);
    unsigned int ord = (ub & 0x80000000u) ? ~ub : (ub | 0x80000000u);
    return ((u64)ord << 32) | (unsigned int)idx;
}

__device__ __forceinline__ void amin_lds(u64* a, u64 k) {
    u64 old = *a;
    while (k < old) {
        u64 prev = atomicCAS(a, old, k);
        if (prev == old) break;
        old = prev;
    }
}

// ---------------- block reduction helpers (blockDim == 256) ----------------
__device__ __forceinline__ float blk_sum(float v, float* red) {
    int t = threadIdx.x;
    red[t] = v; __syncthreads();
    for (int s = 128; s > 0; s >>= 1) {
        if (t < s) red[t] += red[t + s];
        __syncthreads();
    }
    float r = red[0]; __syncthreads();
    return r;
}

__device__ __forceinline__ float blk_max(float v, float* red) {
    int t = threadIdx.x;
    red[t] = v; __syncthreads();
    for (int s = 128; s > 0; s >>= 1) {
        if (t < s) red[t] = fmaxf(red[t], red[t + s]);
        __syncthreads();
    }
    float r = red[0]; __syncthreads();
    return r;
}

__device__ __forceinline__ void split_write(float v, f16* oh, f16* ol, size_t idx) {
    f16 h = (f16)v;
    oh[idx] = h;
    ol[idx] = (f16)((v - (float)h) * 1024.f);
}

__device__ __forceinline__ void buildW_elem(const float* Wr, const float* Wi,
                                            f16* oh, f16* ol, int transp, int idx) {
    int n = idx >> 10, k = idx & 1023;
    int r = transp ? k : n, c = transp ? n : k;
    float v;
    if (r < 512) v = (c < 512) ? Wr[r * 512 + c] : -Wi[r * 512 + (c - 512)];
    else { int r2 = r - 512; v = (c < 512) ? Wi[r2 * 512 + c] : Wr[r2 * 512 + (c - 512)]; }
    split_write(v, oh, ol, idx);
}

// ---------------- fused setup: builders + init + embed + cbnorm + lse ------
__global__ __launch_bounds__(256)
void k_setup(const int* __restrict__ ids, const float* __restrict__ mag,
             const float* __restrict__ phs,
             const float* __restrict__ lin_r, const float* __restrict__ lin_i,
             const float* __restrict__ q_r, const float* __restrict__ q_i,
             const float* __restrict__ k_r, const float* __restrict__ k_i,
             const float* __restrict__ v_r, const float* __restrict__ v_i,
             const float* __restrict__ cb, const float* __restrict__ adj,
             const float* __restrict__ dec_W,
             f16* __restrict__ W1_h, f16* __restrict__ W1_l,
             f16* __restrict__ WqT_h, f16* __restrict__ WqT_l,
             f16* __restrict__ WkT_h, f16* __restrict__ WkT_l,
             f16* __restrict__ Bv_h, f16* __restrict__ Bv_l,
             f16* __restrict__ cb_h, f16* __restrict__ cb_l,
             f16* __restrict__ dW_h,
             f16* __restrict__ zh, f16* __restrict__ zl,
             float* __restrict__ cbn, float* __restrict__ lse,
             float* __restrict__ ptrb, float* __restrict__ remainb,
             float* __restrict__ scal, u64* __restrict__ amin2) {
    __shared__ float red[256];
    int bid = blockIdx.x, t = threadIdx.x;
    if (bid < 4096) {
        buildW_elem(lin_r, lin_i, W1_h, W1_l, 0, bid * 256 + t);
    } else if (bid < 8192) {
        buildW_elem(q_r, q_i, WqT_h, WqT_l, 1, (bid - 4096) * 256 + t);
    } else if (bid < 12288) {
        buildW_elem(k_r, k_i, WkT_h, WkT_l, 1, (bid - 8192) * 256 + t);
    } else if (bid < 16384) {
        buildW_elem(v_r, v_i, Bv_h, Bv_l, 0, (bid - 12288) * 256 + t);
    } else if (bid < 20480) {
        int idx = (bid - 16384) * 256 + t;
        split_write(cb[idx], cb_h, cb_l, idx);
    } else if (bid < 22528) {
        size_t i = (size_t)(bid - 20480) * 256 + t;
        size_t st = (size_t)2048 * 256;
        size_t n = (size_t)NV * ND2;
        for (; i < n; i += st) dW_h[i] = (f16)dec_W[i];
    } else if (bid < 23552) {
        int k = bid - 22528;
        float s = 0.f;
        for (int c = t; c < ND2; c += 256) {
            float v = cb[(size_t)k * ND2 + c];
            s += v * v;
        }
        float tot = blk_sum(s, red);
        if (t == 0) cbn[k] = tot;
    } else if (bid < 24576) {
        int k = bid - 23552;
        float lm = -INFINITY;
        for (int c = t; c < NK; c += 256) lm = fmaxf(lm, adj[(size_t)k * NK + c]);
        float mxa = blk_max(lm, red);
        float le = 0.f;
        for (int c = t; c < NK; c += 256) le += expf(adj[(size_t)k * NK + c] - mxa);
        float se = blk_sum(le, red);
        if (t == 0) lse[k] = mxa + logf(se);
    } else if (bid < 25600) {
        int b = bid - 24576;
        int id = ids[b];
        for (int d = t; d < ND; d += 256) {
            float m = mag[(size_t)id * ND + d];
            float p = phs[(size_t)id * ND + d];
            split_write(m * cosf(p), zh, zl, (size_t)b * ND2 + d);
            split_write(m * sinf(p), zh, zl, (size_t)b * ND2 + ND + d);
        }
    } else {
        int i = (bid - 25600) * 256 + t;
        if (i < NB) {
            remainb[i] = 1.f;
            amin2[i] = ~0ULL;
            amin2[NB + i] = ~0ULL;
            for (int s = 0; s < NSTACK; ++s) ptrb[i * NSTACK + s] = (s == 0) ? 1.f : 0.f;
        }
        if (i < 8) scal[i] = 0.f;
    }
}

// ---------------- in-loop fp16(x2-split) MFMA NT GEMM v9 -------------------
// In-block split-K-2, 64x64 tile, 8 waves. Staging via global_load_lds DMA,
// 3 LDS buffers, counted vmcnt(4).
// EPI 0: f32 C.  EPI 2: combined (sec0 split rows, sec1 transposed split).
// EPI 3: NO C write; fused VQ argmin.
template<int EPI>
__global__ __launch_bounds__(512, 2)
void k_sgemm9(const f16* __restrict__ Ah, const f16* __restrict__ Al,
              const f16* __restrict__ Bh, const f16* __restrict__ Bl,
              float* __restrict__ Cf,
              f16* __restrict__ qh, f16* __restrict__ ql,
              f16* __restrict__ vTh, f16* __restrict__ vTl,
              int N, int K, float alpha,
              const float* __restrict__ cbnv, u64* __restrict__ amin) {
    __shared__ f16 lds[3][2][4][64 * 32];   // [buf][group][Ah,Al,Bh,Bl]  (96 KB)
    __shared__ u64 aml[64];
    const int tid = threadIdx.x;
    const int g = tid >> 8;
    const int lane = tid & 63;
    const int q = (tid >> 6) & 3;
    const int qr = (q >> 1) * 32, qc = (q & 1) * 32;
    const int fr = lane & 15, cbk = lane >> 4;
    const int m0 = blockIdx.y * 64, n0 = blockIdx.x * 64;
    const int kbase = g * (K >> 1);

    const f16* sbase = (q == 0) ? Ah : (q == 1) ? Al : (q == 2) ? Bh : Bl;
    const int rbase = (q < 2) ? m0 : n0;
    const int srow = lane >> 2, pch = lane & 3;

    f32x4 z4 = {0.f, 0.f, 0.f, 0.f};
    f32x4 acc0[2][2] = {{z4, z4}, {z4, z4}};
    f32x4 acc1[2][2] = {{z4, z4}, {z4, z4}};

    auto STAGE = [&](int itn, int nbuf) {
        int ko = kbase + itn * 32;
        #pragma unroll
        for (int c = 0; c < 4; ++c) {
            int row = c * 16 + srow;
            int chunk = (pch ^ ((row >> 1) & 3)) * 8;
            gl16(sbase + (size_t)(rbase + row) * K + ko + chunk,
                 (f16*)&lds[nbuf][g][q][c * 512]);
        }
    };

    auto COMPUTE = [&](int buf) {
        f16x8 ah[2], al[2], bh[2], bl[2];
        #pragma unroll
        for (int i = 0; i < 2; ++i) {
            int ra = qr + i * 16 + fr;
            int oa = swz(ra, cbk);
            ah[i] = *(const f16x8*)&lds[buf][g][0][oa];
            al[i] = *(const f16x8*)&lds[buf][g][1][oa];
            int rb = qc + i * 16 + fr;
            int ob = swz(rb, cbk);
            bh[i] = *(const f16x8*)&lds[buf][g][2][ob];
            bl[i] = *(const f16x8*)&lds[buf][g][3][ob];
        }
        #pragma unroll
        for (int i = 0; i < 2; ++i)
            #pragma unroll
            for (int j = 0; j < 2; ++j) {
                acc0[i][j] = __builtin_amdgcn_mfma_f32_16x16x32_f16(ah[i], bh[j], acc0[i][j], 0, 0, 0);
                acc1[i][j] = __builtin_amdgcn_mfma_f32_16x16x32_f16(ah[i], bl[j], acc1[i][j], 0, 0, 0);
                acc1[i][j] = __builtin_amdgcn_mfma_f32_16x16x32_f16(al[i], bh[j], acc1[i][j], 0, 0, 0);
            }
    };

    STAGE(0, 0);
    STAGE(1, 1);
    asm volatile("s_waitcnt vmcnt(4)" ::: "memory");
    __builtin_amdgcn_sched_barrier(0);
    __builtin_amdgcn_s_barrier();

    for (int it = 0; it < 14; ++it) {
        STAGE(it + 2, (it + 2) % 3);
        COMPUTE(it % 3);
        asm volatile("s_waitcnt vmcnt(4)" ::: "memory");
        __builtin_amdgcn_sched_barrier(0);
        __builtin_amdgcn_s_barrier();
    }
    COMPUTE(14 % 3);
    asm volatile("s_waitcnt vmcnt(0)" ::: "memory");
    __builtin_amdgcn_sched_barrier(0);
    __builtin_amdgcn_s_barrier();
    COMPUTE(15 % 3);
    __syncthreads();

    float val[2][2][4];
    #pragma unroll
    for (int i = 0; i < 2; ++i)
        #pragma unroll
        for (int j = 0; j < 2; ++j)
            #pragma unroll
            for (int jj = 0; jj < 4; ++jj)
                val[i][j][jj] = acc0[i][j][jj] + acc1[i][j][jj] * 9.765625e-4f;

    float* red = (float*)&lds[0][0][0][0];
    if (g == 1) {
        #pragma unroll
        for (int i = 0; i < 2; ++i)
            #pragma unroll
            for (int j = 0; j < 2; ++j) {
                int r = i * 16 + (lane >> 4) * 4, c = j * 16 + (lane & 15);
                #pragma unroll
                for (int jj = 0; jj < 4; ++jj)
                    red[q * 1056 + (r + jj) * 33 + c] = val[i][j][jj];
            }
        if constexpr (EPI == 3) {
            if ((tid & 255) < 64) aml[tid & 255] = ~0ULL;
        }
    }
    __syncthreads();
    if (g == 0) {
        #pragma unroll
        for (int i = 0; i < 2; ++i)
            #pragma unroll
            for (int j = 0; j < 2; ++j) {
                int r = i * 16 + (lane >> 4) * 4, c = j * 16 + (lane & 15);
                #pragma unroll
                for (int jj = 0; jj < 4; ++jj)
                    val[i][j][jj] += red[q * 1056 + (r + jj) * 33 + c];
                int orow = m0 + qr + r;
                int ocol = n0 + qc + c;
                if constexpr (EPI == 0) {
                    #pragma unroll
                    for (int jj = 0; jj < 4; ++jj)
                        Cf[(size_t)(orow + jj) * N + ocol] = alpha * val[i][j][jj];
                } else if constexpr (EPI == 2) {
                    int sec = ocol >> 10, lc = ocol & 1023;
                    if (sec == 0) {
                        #pragma unroll
                        for (int jj = 0; jj < 4; ++jj)
                            split_write(val[i][j][jj], qh, ql, (size_t)(orow + jj) * ND2 + lc);
                    } else {
                        f16x4 th, tl;
                        #pragma unroll
                        for (int jj = 0; jj < 4; ++jj) {
                            float v = val[i][j][jj];
                            f16 h = (f16)v;
                            th[jj] = h;
                            tl[jj] = (f16)((v - (float)h) * 1024.f);
                        }
                        *(f16x4*)&vTh[(size_t)lc * ND2 + orow] = th;
                        *(f16x4*)&vTl[(size_t)lc * ND2 + orow] = tl;
                    }
                } else {
                    float cbv = cbnv[ocol];
                    #pragma unroll
                    for (int jj = 0; jj < 4; ++jj) {
                        float v = cbv - 2.f * val[i][j][jj];
                        amin_lds(&aml[qr + r + jj], fkey(v, ocol));
                    }
                }
            }
    }
    if constexpr (EPI == 3) {
        __syncthreads();
        if (tid < 64) atomicMin(&amin[m0 + tid], aml[tid]);
    }
}

// ---------------- decoder GEMM v9: wave-tile 128x64 from 16x16x32 frags ----
// BM=256, BN=128, BK=32, 256 thr = 4 waves (2M x 2N). Per block-iter:
// 48 frag ds_reads for 128 MFMAs (1.33x fewer than v7), same conflict-free
// pattern, same per-element accumulation order (bit-identical output).
// 3-deep counted-vmcnt DMA pipeline (6 DMAs/wave/stage -> vmcnt(6)).
__global__ __launch_bounds__(256, 2)
void k_dgemm9(const f16* __restrict__ A, const f16* __restrict__ B,
              float* __restrict__ C, const float* __restrict__ bias) {
    __shared__ f16 sA[3][256 * 32];   // 48 KB
    __shared__ f16 sB[3][128 * 32];   // 24 KB
    const int bid = blockIdx.x;               // 0..999 (bijective: 1000 = 8*125)
    const int l2 = (bid & 7) * 125 + (bid >> 3);
    const int m0 = (l2 & 3) * 256;
    const int n0 = (l2 >> 2) * 128;
    const int tid = threadIdx.x;
    const int lane = tid & 63, w = tid >> 6;
    const int wr = (w >> 1) * 128, wc = (w & 1) * 64;
    const int fr = lane & 15, cbk = lane >> 4;
    const int K = ND2;
    const int srow = lane >> 2, pch = lane & 3;

    f32x4 z4 = {0.f, 0.f, 0.f, 0.f};
    f32x4 acc[8][4];
    #pragma unroll
    for (int i = 0; i < 8; ++i)
        #pragma unroll
        for (int j = 0; j < 4; ++j) acc[i][j] = z4;

    auto STAGE = [&](int itn, int nbuf) {
        int ko = itn * 32;
        #pragma unroll
        for (int c = 0; c < 6; ++c) {
            int m = w * 6 + c;                 // 0..23: 16 A-slabs then 8 B-slabs
            if (m < 16) {
                int row = m * 16 + srow;
                int chunk = (pch ^ ((row >> 1) & 3)) * 8;
                gl16(A + (size_t)(m0 + row) * K + ko + chunk, (f16*)&sA[nbuf][m * 512]);
            } else {
                int mm = m - 16;
                int row = mm * 16 + srow;
                int chunk = (pch ^ ((row >> 1) & 3)) * 8;
                gl16(B + (size_t)(n0 + row) * K + ko + chunk, (f16*)&sB[nbuf][mm * 512]);
            }
        }
    };

    auto COMPUTE = [&](int buf) {
        f16x8 a[8], b[4];
        #pragma unroll
        for (int i = 0; i < 8; ++i) {
            int rra = wr + i * 16 + fr;
            a[i] = *(const f16x8*)&sA[buf][swz(rra, cbk)];
        }
        #pragma unroll
        for (int j = 0; j < 4; ++j) {
            int rrb = wc + j * 16 + fr;
            b[j] = *(const f16x8*)&sB[buf][swz(rrb, cbk)];
        }
        #pragma unroll
        for (int i = 0; i < 8; ++i)
            #pragma unroll
            for (int j = 0; j < 4; ++j)
                acc[i][j] = __builtin_amdgcn_mfma_f32_16x16x32_f16(a[i], b[j], acc[i][j], 0, 0, 0);
    };

    STAGE(0, 0);
    STAGE(1, 1);
    asm volatile("s_waitcnt vmcnt(6)" ::: "memory");
    __builtin_amdgcn_sched_barrier(0);
    __builtin_amdgcn_s_barrier();

    for (int it = 0; it < 30; ++it) {
        const int cur = it % 3;
        STAGE(it + 2, (it + 2) % 3);
        COMPUTE(cur);
        asm volatile("s_waitcnt vmcnt(6)" ::: "memory");
        __builtin_amdgcn_sched_barrier(0);
        __builtin_amdgcn_s_barrier();
    }
    COMPUTE(0);
    asm volatile("s_waitcnt vmcnt(0)" ::: "memory");
    __builtin_amdgcn_sched_barrier(0);
    __builtin_amdgcn_s_barrier();
    COMPUTE(1);

    #pragma unroll
    for (int i = 0; i < 8; ++i)
        #pragma unroll
        for (int j = 0; j < 4; ++j) {
            int orow = m0 + wr + i * 16 + (lane >> 4) * 4;
            int ocol = n0 + wc + j * 16 + (lane & 15);
            float bv = bias[ocol];
            #pragma unroll
            for (int jj = 0; jj < 4; ++jj)
                C[(size_t)(orow + jj) * NV + ocol] = acc[i][j][jj] + bv;
        }
}

// ---------------- cnorm + modrelu (row-wise; also builds the Pnorm table) --
__global__ __launch_bounds__(256)
void k_cnorm(const float* __restrict__ p, const float* __restrict__ CW1,
             const int* __restrict__ sym,
             f16* __restrict__ ph, f16* __restrict__ pl,
             const float* __restrict__ scale, const float* __restrict__ shift,
             const float* __restrict__ mbias) {
    __shared__ float red[256];
    int b = blockIdx.x, t = threadIdx.x;
    const float* row = sym ? (CW1 + (size_t)sym[b] * ND2) : (p + (size_t)b * ND2);
    float xr[2], xi[2], hv[2];
    float lsum = 0.f;
    #pragma unroll
    for (int l = 0; l < 2; ++l) {
        int d = t + l * 256;
        float a = row[d], c = row[ND + d];
        xr[l] = a; xi[l] = c;
        float h = sqrtf(a * a + c * c);
        hv[l] = h;
        lsum += h + FEPS;
    }
    float mean = blk_sum(lsum, red) * (1.f / ND);
    float lvar = 0.f;
    #pragma unroll
    for (int l = 0; l < 2; ++l) {
        float dv = (hv[l] + FEPS) - mean;
        lvar += dv * dv;
    }
    float var = blk_sum(lvar, red) * (1.f / (ND - 1));
    float istd = 1.f / sqrtf(var + FEPS);
    #pragma unroll
    for (int l = 0; l < 2; ++l) {
        int d = t + l * 256;
        float nm = ((hv[l] + FEPS) - mean) * istd * scale[d] + shift[d];
        float cc, ss;
        if (hv[l] > 0.f) { cc = xr[l] / hv[l]; ss = xi[l] / hv[l]; }
        else             { cc = 1.f; ss = 0.f; }
        float vr_ = nm * cc, vi_ = nm * ss;
        float n = sqrtf(vr_ * vr_ + vi_ * vi_) + FEPS;
        float aarg = n + mbias[d];
        float sg = (aarg > 0.f ? aarg : 0.f) / n;
        split_write(vr_ * sg, ph, pl, (size_t)b * ND2 + d);
        split_write(vi_ * sg, ph, pl, (size_t)b * ND2 + ND + d);
    }
}

// ---------------- row softmax over f32 S (step 0 only) ----------
__global__ __launch_bounds__(256)
void k_softmax(const float* __restrict__ S, f16* __restrict__ Ah, f16* __restrict__ Al) {
    __shared__ float red[256];
    int row = blockIdx.x, t = threadIdx.x;
    float v[4];
    float lm = -INFINITY;
    #pragma unroll
    for (int l = 0; l < 4; ++l) {
        v[l] = S[(size_t)row * NB + t + l * 256];
        lm = fmaxf(lm, v[l]);
    }
    float mx = blk_max(lm, red);
    float ls = 0.f;
    #pragma unroll
    for (int l = 0; l < 4; ++l) { v[l] = expf(v[l] - mx); ls += v[l]; }
    float tot = blk_sum(ls, red);
    float inv = 1024.f / tot;
    #pragma unroll
    for (int l = 0; l < 4; ++l)
        split_write(v[l] * inv, Ah, Al, (size_t)row * NB + t + l * 256);
}

// ---------------- stack step via coefficient expansion (no memb tensor) ----
__global__ __launch_bounds__(256)
void k_stack2(const float* __restrict__ zfh, int step,
              const float* __restrict__ hW, const float* __restrict__ hB,
              const float* __restrict__ cW, const float* __restrict__ cB,
              float* __restrict__ ptrb, float* __restrict__ Ptab,
              float* __restrict__ haltb, float* __restrict__ cfn,
              f16* __restrict__ cfh, f16* __restrict__ cfl) {
    __shared__ float zfs[ND2];
    __shared__ float red[256];
    __shared__ float pt[NSTACK], npv[NSTACK], wmv[NSTACK];
    __shared__ float coef[NSTEPS];
    __shared__ float snorm;
    int b = blockIdx.x, t = threadIdx.x;
    const float* zf = zfh + (size_t)step * NB * ND2 + (size_t)b * ND2;
    for (int c = t; c < ND2; c += 256) zfs[c] = zf[c];
    __syncthreads();
    float dh = 0, d0 = 0, d1 = 0, d2 = 0;
    for (int c = t; c < ND2; c += 256) {
        float z = zfs[c];
        dh += z * hW[c];
        d0 += z * cW[c];
        d1 += z * cW[ND2 + c];
        d2 += z * cW[2 * ND2 + c];
    }
    dh = blk_sum(dh, red);
    d0 = blk_sum(d0, red);
    d1 = blk_sum(d1, red);
    d2 = blk_sum(d2, red);
    float h = 1.f / (1.f + expf(-(dh + hB[0])));
    float l0 = d0 + cB[0], l1 = d1 + cB[1], l2 = d2 + cB[2];
    float mx = fmaxf(l0, fmaxf(l1, l2));
    float e0 = expf(l0 - mx), e1 = expf(l1 - mx), e2 = expf(l2 - mx);
    float es = e0 + e1 + e2;
    float push = e0 / es, pop = e1 / es, noop = e2 / es;
    if (t < NSTACK) pt[t] = ptrb[b * NSTACK + t];
    __syncthreads();
    if (t < NSTACK) {
        float up = pt[(t + NSTACK - 1) & 15];
        float dn = pt[(t + 1) & 15];
        npv[t] = push * up + pop * dn + noop * pt[t];
        wmv[t] = push * up;
    }
    __syncthreads();
    if (t == 0) {
        float s = 0.f;
        for (int j = 0; j < NSTACK; ++j) s += npv[j];
        snorm = 1.f / (s + FEPS);
    }
    __syncthreads();
    if (t < NSTACK) {
        npv[t] *= snorm;
        ptrb[b * NSTACK + t] = npv[t];
        float om = 1.f - wmv[t];
        for (int u = 0; u < step; ++u)
            Ptab[((size_t)b * NSTEPS + u) * NSTACK + t] *= om;
        Ptab[((size_t)b * NSTEPS + step) * NSTACK + t] = wmv[t];
    }
    __syncthreads();
    if (t <= step) {
        float s = 0.f;
        #pragma unroll
        for (int j = 0; j < NSTACK; ++j)
            s += npv[j] * Ptab[((size_t)b * NSTEPS + t) * NSTACK + j];
        coef[t] = s;
    }
    __syncthreads();
    float lq = 0.f;
    for (int c = t; c < ND2; c += 256) {
        float rd = coef[step] * zfs[c];
        for (int u = 0; u < step; ++u)
            rd += coef[u] * zfh[(size_t)u * NB * ND2 + (size_t)b * ND2 + c];
        float v = zfs[c] + rd;
        split_write(v, cfh, cfl, (size_t)b * ND2 + c);
        lq += v * v;
    }
    float q = blk_sum(lq, red);
    if (t == 0) { cfn[b] = q; haltb[b] = h; }
}

// ---------------- merged VQ step + next-step attention prep ----------------
__global__ __launch_bounds__(256)
void k_vqatt(const u64* __restrict__ aminCur, u64* __restrict__ aminNxt,
             const float* __restrict__ SS,
             const f16* __restrict__ VTh, const f16* __restrict__ VTl,
             f16* __restrict__ Ah, f16* __restrict__ Al,
             f16* __restrict__ vTh, f16* __restrict__ vTl,
             const float* __restrict__ cb, const float* __restrict__ cfn,
             const float* __restrict__ adj, const float* __restrict__ lse,
             const float* __restrict__ haltb,
             float* __restrict__ remainb, float* __restrict__ zw,
             f16* __restrict__ zwh, f16* __restrict__ zwl,
             int* __restrict__ prev, float* __restrict__ scal,
             int step, int islast) {
    __shared__ float red[256];
    __shared__ int syms[NB];
    int t = threadIdx.x;
    if (blockIdx.x < NB) {
        int b = blockIdx.x;
        u64 key = aminCur[b];
        int sym = (int)(key & 0xFFFFFFFFu);
        unsigned int ord = (unsigned int)(key >> 32);
        unsigned int ub = (ord & 0x80000000u) ? (ord & 0x7FFFFFFFu) : ~ord;
        float sval0 = __uint_as_float(ub);
        float sdt = sval0 + cfn[b];
        float contrib = 0.f;
        if (step > 0) {
            int pv = prev[b];
            contrib = lse[pv] - adj[(size_t)pv * NK + sym];
        }
        float hb = haltb[b];
        float rm = remainb[b];
        float w = islast ? rm : hb * rm;
        for (int c = t; c < ND2; c += 256) {
            size_t idx = (size_t)b * ND2 + c;
            float nv = zw[idx] + w * cb[(size_t)sym * ND2 + c];
            if (islast) split_write(nv, zwh, zwl, idx);
            else zw[idx] = nv;
        }
        if (t == 0) {
            float nrm = rm * (1.f - hb);
            remainb[b] = nrm;
            atomicAdd(&scal[0], sdt);
            if (step > 0) atomicAdd(&scal[1], contrib);
            atomicAdd(&scal[2], nrm);
            prev[b] = sym;
            aminNxt[b] = ~0ULL;
        }
    } else {
        for (int i = t; i < NB; i += 256) syms[i] = (int)(aminCur[i] & 0xFFFFFFFFu);
        __syncthreads();
        if (blockIdx.x < 2 * NB) {
            int row = blockIdx.x - NB;
            const float* Srow = SS + (size_t)syms[row] * NK;
            float v[4];
            float lm = -INFINITY;
            #pragma unroll
            for (int l = 0; l < 4; ++l) {
                v[l] = ATT_SCALE * Srow[syms[t + l * 256]];
                lm = fmaxf(lm, v[l]);
            }
            float mx = blk_max(lm, red);
            float ls = 0.f;
            #pragma unroll
            for (int l = 0; l < 4; ++l) { v[l] = expf(v[l] - mx); ls += v[l]; }
            float tot = blk_sum(ls, red);
            float inv = 1024.f / tot;
            #pragma unroll
            for (int l = 0; l < 4; ++l)
                split_write(v[l] * inv, Ah, Al, (size_t)row * NB + t + l * 256);
        } else {
            int n = blockIdx.x - 2 * NB;
            const f16* rh = VTh + (size_t)n * NK;
            const f16* rl = VTl + (size_t)n * NK;
            for (int b = t; b < NB; b += 256) {
                int s = syms[b];
                vTh[(size_t)n * NB + b] = rh[s];
                vTl[(size_t)n * NB + b] = rl[s];
            }
        }
    }
}

__global__ void k_aux(const float* __restrict__ scal, float* __restrict__ out) {
    out[0] = 1.25f * scal[0] / (1024.f * 1024.f)
           + 0.005f * (scal[1] / 1024.f)
           + 0.0001f * (scal[2] / 1024.f);
}

// ---------------- launch ----------------
extern "C" void kernel_launch(void* const* d_in, const int* in_sizes, int n_in,
                              void* d_out, int out_size, void* d_ws, size_t ws_size,
                              hipStream_t stream) {
    const int*   input_ids  = (const int*)  d_in[0];
    const float* emb_mag    = (const float*)d_in[1];
    const float* emb_phase  = (const float*)d_in[2];
    const float* lin_r      = (const float*)d_in[3];
    const float* lin_i      = (const float*)d_in[4];
    const float* norm_scale = (const float*)d_in[5];
    const float* norm_shift = (const float*)d_in[6];
    const float* mod_bias   = (const float*)d_in[7];
    const float* halt_W     = (const float*)d_in[8];
    const float* halt_b     = (const float*)d_in[9];
    const float* ctrl_W     = (const float*)d_in[10];
    const float* ctrl_b     = (const float*)d_in[11];
    const float* q_r        = (const float*)d_in[12];
    const float* q_i        = (const float*)d_in[13];
    const float* k_r        = (const float*)d_in[14];
    const float* k_i        = (const float*)d_in[15];
    const float* v_r        = (const float*)d_in[16];
    const float* v_i        = (const float*)d_in[17];
    const float* codebook   = (const float*)d_in[18];
    const float* adjacency  = (const float*)d_in[19];
    const float* dec_W      = (const float*)d_in[20];
    const float* dec_b      = (const float*)d_in[21];
    float* out = (float*)d_out;

    // ---- workspace carve-up (f32 region, then f16 region) ----
    float* fb = (float*)d_ws;
    size_t o = 0;
    auto af = [&](size_t n) { float* p = fb + o; o += n; return p; };
    float* scr      = af((size_t)NB * ND2);
    float* SS       = af((size_t)NK * NK);
    float* zfh      = af((size_t)NSTEPS * NB * ND2);
    float* CW1      = af((size_t)NK * ND2);
    float* zw       = af((size_t)NB * ND2);
    float* Ptab     = af((size_t)NB * NSTEPS * NSTACK);
    float* ptrb     = af((size_t)NB * NSTACK);
    float* haltb    = af(NB);
    float* remainb  = af(NB);
    float* cbn      = af(NK);
    float* cfn      = af(NB);
    float* lse      = af(NK);
    int*   prev     = (int*)af(NB);
    u64*   amin2    = (u64*)af(4 * NB);
    float* scal     = af(8);

    f16* hbuf = (f16*)(fb + o);
    size_t ho = 0;
    auto ah = [&](size_t n) { f16* q = hbuf + ho; ho += n; return q; };
    f16* z_h   = ah((size_t)NB * ND2);
    f16* z_l   = ah((size_t)NB * ND2);
    f16* p_h   = ah((size_t)NB * ND2);
    f16* p_l   = ah((size_t)NB * ND2);
    f16* t_h   = ah((size_t)NB * ND2);
    f16* t_l   = ah((size_t)NB * ND2);
    f16* vT_h  = ah((size_t)NB * ND2);
    f16* vT_l  = ah((size_t)NB * ND2);
    f16* VTt_h = ah((size_t)ND2 * NK);
    f16* VTt_l = ah((size_t)ND2 * NK);
    f16* Pn_h  = ah((size_t)NK * ND2);
    f16* Pn_l  = ah((size_t)NK * ND2);
    f16* A_h   = ah((size_t)NB * NB);
    f16* A_l   = ah((size_t)NB * NB);
    f16* cf_h  = ah((size_t)NB * ND2);
    f16* cf_l  = ah((size_t)NB * ND2);
    f16* zw_h  = ah((size_t)NB * ND2);
    f16* zw_l  = ah((size_t)NB * ND2);
    f16* W1_h  = ah((size_t)ND2 * ND2);
    f16* W1_l  = ah((size_t)ND2 * ND2);
    f16* WqT_h = ah((size_t)ND2 * ND2);
    f16* WqT_l = ah((size_t)ND2 * ND2);
    f16* WkT_h = ah((size_t)ND2 * ND2);
    f16* WkT_l = ah((size_t)ND2 * ND2);
    f16* Bc_h  = ah((size_t)2 * ND2 * ND2);
    f16* Bc_l  = ah((size_t)2 * ND2 * ND2);
    f16* cb_h  = ah((size_t)NK * ND2);
    f16* cb_l  = ah((size_t)NK * ND2);
    f16* dW_h  = ah((size_t)NV * ND2);

    hipMemsetAsync(zw, 0, (size_t)NB * ND2 * sizeof(float), stream);
    k_setup<<<25604, 256, 0, stream>>>(input_ids, emb_mag, emb_phase,
        lin_r, lin_i, q_r, q_i, k_r, k_i, v_r, v_i, codebook, adjacency, dec_W,
        W1_h, W1_l, WqT_h, WqT_l, WkT_h, WkT_l,
        Bc_h + (size_t)ND2 * ND2, Bc_l + (size_t)ND2 * ND2,
        cb_h, cb_l, dW_h, z_h, z_l, cbn, lse, ptrb, remainb, scal, amin2);
    // M' GEMM writes split Bc rows directly via EPI2 sec0 (N=1024 -> all sec0)
    k_sgemm9<2><<<dim3(16, 16), 512, 0, stream>>>(WkT_h, WkT_l, WqT_h, WqT_l, nullptr,
        Bc_h, Bc_l, nullptr, nullptr, ND2, ND2, 1.f, nullptr, nullptr);
    k_sgemm9<0><<<dim3(16, 16), 512, 0, stream>>>(cb_h, cb_l, W1_h, W1_l, CW1,
        nullptr, nullptr, nullptr, nullptr, ND2, ND2, 1.f, nullptr, nullptr);
    k_cnorm<<<NK, 256, 0, stream>>>(CW1, nullptr, nullptr, Pn_h, Pn_l,
                                    norm_scale, norm_shift, mod_bias);
    k_sgemm9<2><<<dim3(32, 16), 512, 0, stream>>>(Pn_h, Pn_l, Bc_h, Bc_l, nullptr,
        t_h, t_l, VTt_h, VTt_l, 2 * ND2, ND2, 1.f, nullptr, nullptr);
    k_sgemm9<0><<<dim3(16, 16), 512, 0, stream>>>(t_h, t_l, Pn_h, Pn_l, SS,
        nullptr, nullptr, nullptr, nullptr, NK, ND2, 1.f, nullptr, nullptr);

    for (int step = 0; step < NSTEPS; ++step) {
        if (step == 0) {
            k_sgemm9<0><<<dim3(16, 16), 512, 0, stream>>>(z_h, z_l, W1_h, W1_l, scr,
                nullptr, nullptr, nullptr, nullptr, ND2, ND2, 1.f, nullptr, nullptr);
            k_cnorm<<<NB, 256, 0, stream>>>(scr, nullptr, nullptr, p_h, p_l,
                                            norm_scale, norm_shift, mod_bias);
            k_sgemm9<2><<<dim3(32, 16), 512, 0, stream>>>(p_h, p_l, Bc_h, Bc_l, nullptr,
                t_h, t_l, vT_h, vT_l, 2 * ND2, ND2, 1.f, nullptr, nullptr);
            k_sgemm9<0><<<dim3(16, 16), 512, 0, stream>>>(t_h, t_l, p_h, p_l, scr,
                nullptr, nullptr, nullptr, nullptr, NB, ND2, ATT_SCALE, nullptr, nullptr);
            k_softmax<<<NB, 256, 0, stream>>>(scr, A_h, A_l);
        }
        k_sgemm9<0><<<dim3(16, 16), 512, 0, stream>>>(A_h, A_l, vT_h, vT_l,
            zfh + (size_t)step * NB * ND2,
            nullptr, nullptr, nullptr, nullptr, ND2, NB, 9.765625e-4f, nullptr, nullptr);
        k_stack2<<<NB, 256, 0, stream>>>(zfh, step, halt_W, halt_b, ctrl_W, ctrl_b,
                                         ptrb, Ptab, haltb, cfn, cf_h, cf_l);
        k_sgemm9<3><<<dim3(16, 16), 512, 0, stream>>>(cf_h, cf_l, cb_h, cb_l, nullptr,
            nullptr, nullptr, nullptr, nullptr, NK, ND2, 1.f, cbn,
            amin2 + (size_t)(step & 1) * NB);
        int islast = (step == NSTEPS - 1) ? 1 : 0;
        int grid = islast ? NB : 3 * NB;
        k_vqatt<<<grid, 256, 0, stream>>>(amin2 + (size_t)(step & 1) * NB,
                                          amin2 + (size_t)((step + 1) & 1) * NB,
                                          SS, VTt_h, VTt_l, A_h, A_l, vT_h, vT_l,
                                          codebook, cfn, adjacency, lse, haltb, remainb,
                                          zw, zw_h, zw_l, prev, scal, step, islast);
    }
    k_dgemm9<<<1000, 256, 0, stream>>>(zw_h, dW_h, out, dec_b);
    k_aux<<<1, 1, 0, stream>>>(scal, out + (size_t)NB * NV);
}

// Round 19
// 1148.423 us; speedup vs baseline: 1.0132x; 1.0132x over previous
//
#include <hip/hip_runtime.h>
#include <math.h>

#define NB 1024
#define ND 512
#define ND2 1024
#define NSTEPS 8
#define NSTACK 16
#define NK 1024
#define NV 32000
#define FEPS 1e-6f
#define ATT_SCALE 0.044194173824159216f

typedef _Float16 f16;
typedef f16 f16x8 __attribute__((ext_vector_type(8)));
typedef f16 f16x4 __attribute__((ext_vector_type(4)));
typedef float f32x4 __attribute__((ext_vector_type(4)));
typedef unsigned long long u64;

// LDS layout: row stride 32 halfs (64B), 16B-chunk swizzle (0 conflicts, r7-verified)
__device__ __forceinline__ int swz(int row, int chunk) {
    return row * 32 + ((chunk ^ ((row >> 1) & 3)) * 8);
}

__device__ __forceinline__ void gl16(const f16* g, f16* l) {
    __builtin_amdgcn_global_load_lds(
        (const __attribute__((address_space(1))) void*)g,
        (__attribute__((address_space(3))) void*)l, 16, 0, 0);
}

// ordered-float encode: monotone u32; key = (ord<<32)|idx, global min == (min val, min idx)
__device__ __forceinline__ u64 fkey(float v, int idx) {
    unsigned int ub = __float_as_uint(v);
    unsigned int ord = (ub & 0x80000000u) ? ~ub : (ub | 0x80000000u);
    return ((u64)ord << 32) | (unsigned int)idx;
}

__device__ __forceinline__ void amin_lds(u64* a, u64 k) {
    u64 old = *a;
    while (k < old) {
        u64 prev = atomicCAS(a, old, k);
        if (prev == old) break;
        old = prev;
    }
}

// ---------------- block reduction helpers (blockDim == 256) ----------------
__device__ __forceinline__ float blk_sum(float v, float* red) {
    int t = threadIdx.x;
    red[t] = v; __syncthreads();
    for (int s = 128; s > 0; s >>= 1) {
        if (t < s) red[t] += red[t + s];
        __syncthreads();
    }
    float r = red[0]; __syncthreads();
    return r;
}

__device__ __forceinline__ float blk_max(float v, float* red) {
    int t = threadIdx.x;
    red[t] = v; __syncthreads();
    for (int s = 128; s > 0; s >>= 1) {
        if (t < s) red[t] = fmaxf(red[t], red[t + s]);
        __syncthreads();
    }
    float r = red[0]; __syncthreads();
    return r;
}

__device__ __forceinline__ void split_write(float v, f16* oh, f16* ol, size_t idx) {
    f16 h = (f16)v;
    oh[idx] = h;
    ol[idx] = (f16)((v - (float)h) * 1024.f);
}

__device__ __forceinline__ void buildW_elem(const float* Wr, const float* Wi,
                                            f16* oh, f16* ol, int transp, int idx) {
    int n = idx >> 10, k = idx & 1023;
    int r = transp ? k : n, c = transp ? n : k;
    float v;
    if (r < 512) v = (c < 512) ? Wr[r * 512 + c] : -Wi[r * 512 + (c - 512)];
    else { int r2 = r - 512; v = (c < 512) ? Wi[r2 * 512 + c] : Wr[r2 * 512 + (c - 512)]; }
    split_write(v, oh, ol, idx);
}

// ---------------- fused setup: builders + init + embed + cbnorm + lse ------
__global__ __launch_bounds__(256)
void k_setup(const int* __restrict__ ids, const float* __restrict__ mag,
             const float* __restrict__ phs,
             const float* __restrict__ lin_r, const float* __restrict__ lin_i,
             const float* __restrict__ q_r, const float* __restrict__ q_i,
             const float* __restrict__ k_r, const float* __restrict__ k_i,
             const float* __restrict__ v_r, const float* __restrict__ v_i,
             const float* __restrict__ cb, const float* __restrict__ adj,
             const float* __restrict__ dec_W,
             f16* __restrict__ W1_h, f16* __restrict__ W1_l,
             f16* __restrict__ WqT_h, f16* __restrict__ WqT_l,
             f16* __restrict__ WkT_h, f16* __restrict__ WkT_l,
             f16* __restrict__ Bv_h, f16* __restrict__ Bv_l,
             f16* __restrict__ cb_h, f16* __restrict__ cb_l,
             f16* __restrict__ dW_h,
             f16* __restrict__ zh, f16* __restrict__ zl,
             float* __restrict__ cbn, float* __restrict__ lse,
             float* __restrict__ ptrb, float* __restrict__ remainb,
             float* __restrict__ scal, u64* __restrict__ amin2) {
    __shared__ float red[256];
    int bid = blockIdx.x, t = threadIdx.x;
    if (bid < 4096) {
        buildW_elem(lin_r, lin_i, W1_h, W1_l, 0, bid * 256 + t);
    } else if (bid < 8192) {
        buildW_elem(q_r, q_i, WqT_h, WqT_l, 1, (bid - 4096) * 256 + t);
    } else if (bid < 12288) {
        buildW_elem(k_r, k_i, WkT_h, WkT_l, 1, (bid - 8192) * 256 + t);
    } else if (bid < 16384) {
        buildW_elem(v_r, v_i, Bv_h, Bv_l, 0, (bid - 12288) * 256 + t);
    } else if (bid < 20480) {
        int idx = (bid - 16384) * 256 + t;
        split_write(cb[idx], cb_h, cb_l, idx);
    } else if (bid < 22528) {
        size_t i = (size_t)(bid - 20480) * 256 + t;
        size_t st = (size_t)2048 * 256;
        size_t n = (size_t)NV * ND2;
        for (; i < n; i += st) dW_h[i] = (f16)dec_W[i];
    } else if (bid < 23552) {
        int k = bid - 22528;
        float s = 0.f;
        for (int c = t; c < ND2; c += 256) {
            float v = cb[(size_t)k * ND2 + c];
            s += v * v;
        }
        float tot = blk_sum(s, red);
        if (t == 0) cbn[k] = tot;
    } else if (bid < 24576) {
        int k = bid - 23552;
        float lm = -INFINITY;
        for (int c = t; c < NK; c += 256) lm = fmaxf(lm, adj[(size_t)k * NK + c]);
        float mxa = blk_max(lm, red);
        float le = 0.f;
        for (int c = t; c < NK; c += 256) le += expf(adj[(size_t)k * NK + c] - mxa);
        float se = blk_sum(le, red);
        if (t == 0) lse[k] = mxa + logf(se);
    } else if (bid < 25600) {
        int b = bid - 24576;
        int id = ids[b];
        for (int d = t; d < ND; d += 256) {
            float m = mag[(size_t)id * ND + d];
            float p = phs[(size_t)id * ND + d];
            split_write(m * cosf(p), zh, zl, (size_t)b * ND2 + d);
            split_write(m * sinf(p), zh, zl, (size_t)b * ND2 + ND + d);
        }
    } else {
        int i = (bid - 25600) * 256 + t;
        if (i < NB) {
            remainb[i] = 1.f;
            amin2[i] = ~0ULL;
            amin2[NB + i] = ~0ULL;
            for (int s = 0; s < NSTACK; ++s) ptrb[i * NSTACK + s] = (s == 0) ? 1.f : 0.f;
        }
        if (i < 8) scal[i] = 0.f;
    }
}

// ---------------- in-loop fp16(x2-split) MFMA NT GEMM v9 -------------------
// In-block split-K-2, 64x64 tile, 8 waves. Staging via global_load_lds DMA,
// 3 LDS buffers, counted vmcnt(4).
// EPI 0: f32 C.  EPI 2: combined (sec0 split rows, sec1 transposed split).
// EPI 3: NO C write; fused VQ argmin.
template<int EPI>
__global__ __launch_bounds__(512, 2)
void k_sgemm9(const f16* __restrict__ Ah, const f16* __restrict__ Al,
              const f16* __restrict__ Bh, const f16* __restrict__ Bl,
              float* __restrict__ Cf,
              f16* __restrict__ qh, f16* __restrict__ ql,
              f16* __restrict__ vTh, f16* __restrict__ vTl,
              int N, int K, float alpha,
              const float* __restrict__ cbnv, u64* __restrict__ amin) {
    __shared__ f16 lds[3][2][4][64 * 32];   // [buf][group][Ah,Al,Bh,Bl]  (96 KB)
    __shared__ u64 aml[64];
    const int tid = threadIdx.x;
    const int g = tid >> 8;
    const int lane = tid & 63;
    const int q = (tid >> 6) & 3;
    const int qr = (q >> 1) * 32, qc = (q & 1) * 32;
    const int fr = lane & 15, cbk = lane >> 4;
    const int m0 = blockIdx.y * 64, n0 = blockIdx.x * 64;
    const int kbase = g * (K >> 1);

    const f16* sbase = (q == 0) ? Ah : (q == 1) ? Al : (q == 2) ? Bh : Bl;
    const int rbase = (q < 2) ? m0 : n0;
    const int srow = lane >> 2, pch = lane & 3;

    f32x4 z4 = {0.f, 0.f, 0.f, 0.f};
    f32x4 acc0[2][2] = {{z4, z4}, {z4, z4}};
    f32x4 acc1[2][2] = {{z4, z4}, {z4, z4}};

    auto STAGE = [&](int itn, int nbuf) {
        int ko = kbase + itn * 32;
        #pragma unroll
        for (int c = 0; c < 4; ++c) {
            int row = c * 16 + srow;
            int chunk = (pch ^ ((row >> 1) & 3)) * 8;
            gl16(sbase + (size_t)(rbase + row) * K + ko + chunk,
                 (f16*)&lds[nbuf][g][q][c * 512]);
        }
    };

    auto COMPUTE = [&](int buf) {
        f16x8 ah[2], al[2], bh[2], bl[2];
        #pragma unroll
        for (int i = 0; i < 2; ++i) {
            int ra = qr + i * 16 + fr;
            int oa = swz(ra, cbk);
            ah[i] = *(const f16x8*)&lds[buf][g][0][oa];
            al[i] = *(const f16x8*)&lds[buf][g][1][oa];
            int rb = qc + i * 16 + fr;
            int ob = swz(rb, cbk);
            bh[i] = *(const f16x8*)&lds[buf][g][2][ob];
            bl[i] = *(const f16x8*)&lds[buf][g][3][ob];
        }
        #pragma unroll
        for (int i = 0; i < 2; ++i)
            #pragma unroll
            for (int j = 0; j < 2; ++j) {
                acc0[i][j] = __builtin_amdgcn_mfma_f32_16x16x32_f16(ah[i], bh[j], acc0[i][j], 0, 0, 0);
                acc1[i][j] = __builtin_amdgcn_mfma_f32_16x16x32_f16(ah[i], bl[j], acc1[i][j], 0, 0, 0);
                acc1[i][j] = __builtin_amdgcn_mfma_f32_16x16x32_f16(al[i], bh[j], acc1[i][j], 0, 0, 0);
            }
    };

    STAGE(0, 0);
    STAGE(1, 1);
    asm volatile("s_waitcnt vmcnt(4)" ::: "memory");
    __builtin_amdgcn_sched_barrier(0);
    __builtin_amdgcn_s_barrier();

    for (int it = 0; it < 14; ++it) {
        STAGE(it + 2, (it + 2) % 3);
        COMPUTE(it % 3);
        asm volatile("s_waitcnt vmcnt(4)" ::: "memory");
        __builtin_amdgcn_sched_barrier(0);
        __builtin_amdgcn_s_barrier();
    }
    COMPUTE(14 % 3);
    asm volatile("s_waitcnt vmcnt(0)" ::: "memory");
    __builtin_amdgcn_sched_barrier(0);
    __builtin_amdgcn_s_barrier();
    COMPUTE(15 % 3);
    __syncthreads();

    float val[2][2][4];
    #pragma unroll
    for (int i = 0; i < 2; ++i)
        #pragma unroll
        for (int j = 0; j < 2; ++j)
            #pragma unroll
            for (int jj = 0; jj < 4; ++jj)
                val[i][j][jj] = acc0[i][j][jj] + acc1[i][j][jj] * 9.765625e-4f;

    float* red = (float*)&lds[0][0][0][0];
    if (g == 1) {
        #pragma unroll
        for (int i = 0; i < 2; ++i)
            #pragma unroll
            for (int j = 0; j < 2; ++j) {
                int r = i * 16 + (lane >> 4) * 4, c = j * 16 + (lane & 15);
                #pragma unroll
                for (int jj = 0; jj < 4; ++jj)
                    red[q * 1056 + (r + jj) * 33 + c] = val[i][j][jj];
            }
        if constexpr (EPI == 3) {
            if ((tid & 255) < 64) aml[tid & 255] = ~0ULL;
        }
    }
    __syncthreads();
    if (g == 0) {
        #pragma unroll
        for (int i = 0; i < 2; ++i)
            #pragma unroll
            for (int j = 0; j < 2; ++j) {
                int r = i * 16 + (lane >> 4) * 4, c = j * 16 + (lane & 15);
                #pragma unroll
                for (int jj = 0; jj < 4; ++jj)
                    val[i][j][jj] += red[q * 1056 + (r + jj) * 33 + c];
                int orow = m0 + qr + r;
                int ocol = n0 + qc + c;
                if constexpr (EPI == 0) {
                    #pragma unroll
                    for (int jj = 0; jj < 4; ++jj)
                        Cf[(size_t)(orow + jj) * N + ocol] = alpha * val[i][j][jj];
                } else if constexpr (EPI == 2) {
                    int sec = ocol >> 10, lc = ocol & 1023;
                    if (sec == 0) {
                        #pragma unroll
                        for (int jj = 0; jj < 4; ++jj)
                            split_write(val[i][j][jj], qh, ql, (size_t)(orow + jj) * ND2 + lc);
                    } else {
                        f16x4 th, tl;
                        #pragma unroll
                        for (int jj = 0; jj < 4; ++jj) {
                            float v = val[i][j][jj];
                            f16 h = (f16)v;
                            th[jj] = h;
                            tl[jj] = (f16)((v - (float)h) * 1024.f);
                        }
                        *(f16x4*)&vTh[(size_t)lc * ND2 + orow] = th;
                        *(f16x4*)&vTl[(size_t)lc * ND2 + orow] = tl;
                    }
                } else {
                    float cbv = cbnv[ocol];
                    #pragma unroll
                    for (int jj = 0; jj < 4; ++jj) {
                        float v = cbv - 2.f * val[i][j][jj];
                        amin_lds(&aml[qr + r + jj], fkey(v, ocol));
                    }
                }
            }
    }
    if constexpr (EPI == 3) {
        __syncthreads();
        if (tid < 64) atomicMin(&amin[m0 + tid], aml[tid]);
    }
}

// ---------------- decoder GEMM v7: counted-vmcnt 3-deep DMA pipeline -------
// BM=256, BN=128, BK=32, 512 thr = 8 waves (4M x 2N), wave tile 64x64.
// Empirical optimum (v8 32x32-frag and v9 128x64-tile both regressed:
// occupancy/latency-hiding dominates LDS-inst economy at this point).
__global__ __launch_bounds__(512, 2)
void k_dgemm7(const f16* __restrict__ A, const f16* __restrict__ B,
              float* __restrict__ C, const float* __restrict__ bias) {
    __shared__ f16 sA[3][256 * 32];   // 48 KB
    __shared__ f16 sB[3][128 * 32];   // 24 KB
    const int bid = blockIdx.x;               // 0..999 (bijective: 1000 = 8*125)
    const int l2 = (bid & 7) * 125 + (bid >> 3);
    const int m0 = (l2 & 3) * 256;
    const int n0 = (l2 >> 2) * 128;
    const int tid = threadIdx.x;
    const int lane = tid & 63, w = tid >> 6;
    const int wr = (w >> 1) * 64, wc = (w & 1) * 64;
    const int fr = lane & 15, cbk = lane >> 4;
    const int K = ND2;
    const int srow = lane >> 2, pch = lane & 3;

    f32x4 z4 = {0.f, 0.f, 0.f, 0.f};
    f32x4 acc[4][4];
    #pragma unroll
    for (int i = 0; i < 4; ++i)
        #pragma unroll
        for (int j = 0; j < 4; ++j) acc[i][j] = z4;

    auto STAGE = [&](int itn, int nbuf) {
        int ko = itn * 32;
        #pragma unroll
        for (int c = 0; c < 3; ++c) {
            int m = w * 3 + c;
            if (m < 16) {
                int row = m * 16 + srow;
                int chunk = (pch ^ ((row >> 1) & 3)) * 8;
                gl16(A + (size_t)(m0 + row) * K + ko + chunk, (f16*)&sA[nbuf][m * 512]);
            } else {
                int mm = m - 16;
                int row = mm * 16 + srow;
                int chunk = (pch ^ ((row >> 1) & 3)) * 8;
                gl16(B + (size_t)(n0 + row) * K + ko + chunk, (f16*)&sB[nbuf][mm * 512]);
            }
        }
    };

    auto COMPUTE = [&](int buf) {
        f16x8 a[4], b[4];
        #pragma unroll
        for (int i = 0; i < 4; ++i) {
            int rra = wr + i * 16 + fr;
            a[i] = *(const f16x8*)&sA[buf][swz(rra, cbk)];
        }
        #pragma unroll
        for (int j = 0; j < 4; ++j) {
            int rrb = wc + j * 16 + fr;
            b[j] = *(const f16x8*)&sB[buf][swz(rrb, cbk)];
        }
        #pragma unroll
        for (int i = 0; i < 4; ++i)
            #pragma unroll
            for (int j = 0; j < 4; ++j)
                acc[i][j] = __builtin_amdgcn_mfma_f32_16x16x32_f16(a[i], b[j], acc[i][j], 0, 0, 0);
    };

    STAGE(0, 0);
    STAGE(1, 1);
    asm volatile("s_waitcnt vmcnt(3)" ::: "memory");
    __builtin_amdgcn_sched_barrier(0);
    __builtin_amdgcn_s_barrier();

    for (int it = 0; it < 30; ++it) {
        const int cur = it % 3;
        STAGE(it + 2, (it + 2) % 3);
        COMPUTE(cur);
        asm volatile("s_waitcnt vmcnt(3)" ::: "memory");
        __builtin_amdgcn_sched_barrier(0);
        __builtin_amdgcn_s_barrier();
    }
    COMPUTE(0);
    asm volatile("s_waitcnt vmcnt(0)" ::: "memory");
    __builtin_amdgcn_sched_barrier(0);
    __builtin_amdgcn_s_barrier();
    COMPUTE(1);

    #pragma unroll
    for (int i = 0; i < 4; ++i)
        #pragma unroll
        for (int j = 0; j < 4; ++j) {
            int orow = m0 + wr + i * 16 + (lane >> 4) * 4;
            int ocol = n0 + wc + j * 16 + (lane & 15);
            float bv = bias[ocol];
            #pragma unroll
            for (int jj = 0; jj < 4; ++jj)
                C[(size_t)(orow + jj) * NV + ocol] = acc[i][j][jj] + bv;
        }
}

// ---------------- cnorm + modrelu (row-wise; also builds the Pnorm table) --
__global__ __launch_bounds__(256)
void k_cnorm(const float* __restrict__ p, const float* __restrict__ CW1,
             const int* __restrict__ sym,
             f16* __restrict__ ph, f16* __restrict__ pl,
             const float* __restrict__ scale, const float* __restrict__ shift,
             const float* __restrict__ mbias) {
    __shared__ float red[256];
    int b = blockIdx.x, t = threadIdx.x;
    const float* row = sym ? (CW1 + (size_t)sym[b] * ND2) : (p + (size_t)b * ND2);
    float xr[2], xi[2], hv[2];
    float lsum = 0.f;
    #pragma unroll
    for (int l = 0; l < 2; ++l) {
        int d = t + l * 256;
        float a = row[d], c = row[ND + d];
        xr[l] = a; xi[l] = c;
        float h = sqrtf(a * a + c * c);
        hv[l] = h;
        lsum += h + FEPS;
    }
    float mean = blk_sum(lsum, red) * (1.f / ND);
    float lvar = 0.f;
    #pragma unroll
    for (int l = 0; l < 2; ++l) {
        float dv = (hv[l] + FEPS) - mean;
        lvar += dv * dv;
    }
    float var = blk_sum(lvar, red) * (1.f / (ND - 1));
    float istd = 1.f / sqrtf(var + FEPS);
    #pragma unroll
    for (int l = 0; l < 2; ++l) {
        int d = t + l * 256;
        float nm = ((hv[l] + FEPS) - mean) * istd * scale[d] + shift[d];
        float cc, ss;
        if (hv[l] > 0.f) { cc = xr[l] / hv[l]; ss = xi[l] / hv[l]; }
        else             { cc = 1.f; ss = 0.f; }
        float vr_ = nm * cc, vi_ = nm * ss;
        float n = sqrtf(vr_ * vr_ + vi_ * vi_) + FEPS;
        float aarg = n + mbias[d];
        float sg = (aarg > 0.f ? aarg : 0.f) / n;
        split_write(vr_ * sg, ph, pl, (size_t)b * ND2 + d);
        split_write(vi_ * sg, ph, pl, (size_t)b * ND2 + ND + d);
    }
}

// ---------------- row softmax over f32 S (step 0 only) ----------
__global__ __launch_bounds__(256)
void k_softmax(const float* __restrict__ S, f16* __restrict__ Ah, f16* __restrict__ Al) {
    __shared__ float red[256];
    int row = blockIdx.x, t = threadIdx.x;
    float v[4];
    float lm = -INFINITY;
    #pragma unroll
    for (int l = 0; l < 4; ++l) {
        v[l] = S[(size_t)row * NB + t + l * 256];
        lm = fmaxf(lm, v[l]);
    }
    float mx = blk_max(lm, red);
    float ls = 0.f;
    #pragma unroll
    for (int l = 0; l < 4; ++l) { v[l] = expf(v[l] - mx); ls += v[l]; }
    float tot = blk_sum(ls, red);
    float inv = 1024.f / tot;
    #pragma unroll
    for (int l = 0; l < 4; ++l)
        split_write(v[l] * inv, Ah, Al, (size_t)row * NB + t + l * 256);
}

// ---------------- stack step via coefficient expansion (no memb tensor) ----
__global__ __launch_bounds__(256)
void k_stack2(const float* __restrict__ zfh, int step,
              const float* __restrict__ hW, const float* __restrict__ hB,
              const float* __restrict__ cW, const float* __restrict__ cB,
              float* __restrict__ ptrb, float* __restrict__ Ptab,
              float* __restrict__ haltb, float* __restrict__ cfn,
              f16* __restrict__ cfh, f16* __restrict__ cfl) {
    __shared__ float zfs[ND2];
    __shared__ float red[256];
    __shared__ float pt[NSTACK], npv[NSTACK], wmv[NSTACK];
    __shared__ float coef[NSTEPS];
    __shared__ float snorm;
    int b = blockIdx.x, t = threadIdx.x;
    const float* zf = zfh + (size_t)step * NB * ND2 + (size_t)b * ND2;
    for (int c = t; c < ND2; c += 256) zfs[c] = zf[c];
    __syncthreads();
    float dh = 0, d0 = 0, d1 = 0, d2 = 0;
    for (int c = t; c < ND2; c += 256) {
        float z = zfs[c];
        dh += z * hW[c];
        d0 += z * cW[c];
        d1 += z * cW[ND2 + c];
        d2 += z * cW[2 * ND2 + c];
    }
    dh = blk_sum(dh, red);
    d0 = blk_sum(d0, red);
    d1 = blk_sum(d1, red);
    d2 = blk_sum(d2, red);
    float h = 1.f / (1.f + expf(-(dh + hB[0])));
    float l0 = d0 + cB[0], l1 = d1 + cB[1], l2 = d2 + cB[2];
    float mx = fmaxf(l0, fmaxf(l1, l2));
    float e0 = expf(l0 - mx), e1 = expf(l1 - mx), e2 = expf(l2 - mx);
    float es = e0 + e1 + e2;
    float push = e0 / es, pop = e1 / es, noop = e2 / es;
    if (t < NSTACK) pt[t] = ptrb[b * NSTACK + t];
    __syncthreads();
    if (t < NSTACK) {
        float up = pt[(t + NSTACK - 1) & 15];
        float dn = pt[(t + 1) & 15];
        npv[t] = push * up + pop * dn + noop * pt[t];
        wmv[t] = push * up;
    }
    __syncthreads();
    if (t == 0) {
        float s = 0.f;
        for (int j = 0; j < NSTACK; ++j) s += npv[j];
        snorm = 1.f / (s + FEPS);
    }
    __syncthreads();
    if (t < NSTACK) {
        npv[t] *= snorm;
        ptrb[b * NSTACK + t] = npv[t];
        float om = 1.f - wmv[t];
        for (int u = 0; u < step; ++u)
            Ptab[((size_t)b * NSTEPS + u) * NSTACK + t] *= om;
        Ptab[((size_t)b * NSTEPS + step) * NSTACK + t] = wmv[t];
    }
    __syncthreads();
    if (t <= step) {
        float s = 0.f;
        #pragma unroll
        for (int j = 0; j < NSTACK; ++j)
            s += npv[j] * Ptab[((size_t)b * NSTEPS + t) * NSTACK + j];
        coef[t] = s;
    }
    __syncthreads();
    float lq = 0.f;
    for (int c = t; c < ND2; c += 256) {
        float rd = coef[step] * zfs[c];
        for (int u = 0; u < step; ++u)
            rd += coef[u] * zfh[(size_t)u * NB * ND2 + (size_t)b * ND2 + c];
        float v = zfs[c] + rd;
        split_write(v, cfh, cfl, (size_t)b * ND2 + c);
        lq += v * v;
    }
    float q = blk_sum(lq, red);
    if (t == 0) { cfn[b] = q; haltb[b] = h; }
}

// ---------------- merged VQ step + next-step attention prep ----------------
__global__ __launch_bounds__(256)
void k_vqatt(const u64* __restrict__ aminCur, u64* __restrict__ aminNxt,
             const float* __restrict__ SS,
             const f16* __restrict__ VTh, const f16* __restrict__ VTl,
             f16* __restrict__ Ah, f16* __restrict__ Al,
             f16* __restrict__ vTh, f16* __restrict__ vTl,
             const float* __restrict__ cb, const float* __restrict__ cfn,
             const float* __restrict__ adj, const float* __restrict__ lse,
             const float* __restrict__ haltb,
             float* __restrict__ remainb, float* __restrict__ zw,
             f16* __restrict__ zwh, f16* __restrict__ zwl,
             int* __restrict__ prev, float* __restrict__ scal,
             int step, int islast) {
    __shared__ float red[256];
    __shared__ int syms[NB];
    int t = threadIdx.x;
    if (blockIdx.x < NB) {
        int b = blockIdx.x;
        u64 key = aminCur[b];
        int sym = (int)(key & 0xFFFFFFFFu);
        unsigned int ord = (unsigned int)(key >> 32);
        unsigned int ub = (ord & 0x80000000u) ? (ord & 0x7FFFFFFFu) : ~ord;
        float sval0 = __uint_as_float(ub);
        float sdt = sval0 + cfn[b];
        float contrib = 0.f;
        if (step > 0) {
            int pv = prev[b];
            contrib = lse[pv] - adj[(size_t)pv * NK + sym];
        }
        float hb = haltb[b];
        float rm = remainb[b];
        float w = islast ? rm : hb * rm;
        for (int c = t; c < ND2; c += 256) {
            size_t idx = (size_t)b * ND2 + c;
            float nv = zw[idx] + w * cb[(size_t)sym * ND2 + c];
            if (islast) split_write(nv, zwh, zwl, idx);
            else zw[idx] = nv;
        }
        if (t == 0) {
            float nrm = rm * (1.f - hb);
            remainb[b] = nrm;
            atomicAdd(&scal[0], sdt);
            if (step > 0) atomicAdd(&scal[1], contrib);
            atomicAdd(&scal[2], nrm);
            prev[b] = sym;
            aminNxt[b] = ~0ULL;
        }
    } else {
        for (int i = t; i < NB; i += 256) syms[i] = (int)(aminCur[i] & 0xFFFFFFFFu);
        __syncthreads();
        if (blockIdx.x < 2 * NB) {
            int row = blockIdx.x - NB;
            const float* Srow = SS + (size_t)syms[row] * NK;
            float v[4];
            float lm = -INFINITY;
            #pragma unroll
            for (int l = 0; l < 4; ++l) {
                v[l] = ATT_SCALE * Srow[syms[t + l * 256]];
                lm = fmaxf(lm, v[l]);
            }
            float mx = blk_max(lm, red);
            float ls = 0.f;
            #pragma unroll
            for (int l = 0; l < 4; ++l) { v[l] = expf(v[l] - mx); ls += v[l]; }
            float tot = blk_sum(ls, red);
            float inv = 1024.f / tot;
            #pragma unroll
            for (int l = 0; l < 4; ++l)
                split_write(v[l] * inv, Ah, Al, (size_t)row * NB + t + l * 256);
        } else {
            int n = blockIdx.x - 2 * NB;
            const f16* rh = VTh + (size_t)n * NK;
            const f16* rl = VTl + (size_t)n * NK;
            for (int b = t; b < NB; b += 256) {
                int s = syms[b];
                vTh[(size_t)n * NB + b] = rh[s];
                vTl[(size_t)n * NB + b] = rl[s];
            }
        }
    }
}

__global__ void k_aux(const float* __restrict__ scal, float* __restrict__ out) {
    out[0] = 1.25f * scal[0] / (1024.f * 1024.f)
           + 0.005f * (scal[1] / 1024.f)
           + 0.0001f * (scal[2] / 1024.f);
}

// ---------------- launch ----------------
extern "C" void kernel_launch(void* const* d_in, const int* in_sizes, int n_in,
                              void* d_out, int out_size, void* d_ws, size_t ws_size,
                              hipStream_t stream) {
    const int*   input_ids  = (const int*)  d_in[0];
    const float* emb_mag    = (const float*)d_in[1];
    const float* emb_phase  = (const float*)d_in[2];
    const float* lin_r      = (const float*)d_in[3];
    const float* lin_i      = (const float*)d_in[4];
    const float* norm_scale = (const float*)d_in[5];
    const float* norm_shift = (const float*)d_in[6];
    const float* mod_bias   = (const float*)d_in[7];
    const float* halt_W     = (const float*)d_in[8];
    const float* halt_b     = (const float*)d_in[9];
    const float* ctrl_W     = (const float*)d_in[10];
    const float* ctrl_b     = (const float*)d_in[11];
    const float* q_r        = (const float*)d_in[12];
    const float* q_i        = (const float*)d_in[13];
    const float* k_r        = (const float*)d_in[14];
    const float* k_i        = (const float*)d_in[15];
    const float* v_r        = (const float*)d_in[16];
    const float* v_i        = (const float*)d_in[17];
    const float* codebook   = (const float*)d_in[18];
    const float* adjacency  = (const float*)d_in[19];
    const float* dec_W      = (const float*)d_in[20];
    const float* dec_b      = (const float*)d_in[21];
    float* out = (float*)d_out;

    // ---- workspace carve-up (f32 region, then f16 region) ----
    float* fb = (float*)d_ws;
    size_t o = 0;
    auto af = [&](size_t n) { float* p = fb + o; o += n; return p; };
    float* scr      = af((size_t)NB * ND2);
    float* SS       = af((size_t)NK * NK);
    float* zfh      = af((size_t)NSTEPS * NB * ND2);
    float* CW1      = af((size_t)NK * ND2);
    float* zw       = af((size_t)NB * ND2);
    float* Ptab     = af((size_t)NB * NSTEPS * NSTACK);
    float* ptrb     = af((size_t)NB * NSTACK);
    float* haltb    = af(NB);
    float* remainb  = af(NB);
    float* cbn      = af(NK);
    float* cfn      = af(NB);
    float* lse      = af(NK);
    int*   prev     = (int*)af(NB);
    u64*   amin2    = (u64*)af(4 * NB);
    float* scal     = af(8);

    f16* hbuf = (f16*)(fb + o);
    size_t ho = 0;
    auto ah = [&](size_t n) { f16* q = hbuf + ho; ho += n; return q; };
    f16* z_h   = ah((size_t)NB * ND2);
    f16* z_l   = ah((size_t)NB * ND2);
    f16* p_h   = ah((size_t)NB * ND2);
    f16* p_l   = ah((size_t)NB * ND2);
    f16* t_h   = ah((size_t)NB * ND2);
    f16* t_l   = ah((size_t)NB * ND2);
    f16* vT_h  = ah((size_t)NB * ND2);
    f16* vT_l  = ah((size_t)NB * ND2);
    f16* VTt_h = ah((size_t)ND2 * NK);
    f16* VTt_l = ah((size_t)ND2 * NK);
    f16* Pn_h  = ah((size_t)NK * ND2);
    f16* Pn_l  = ah((size_t)NK * ND2);
    f16* A_h   = ah((size_t)NB * NB);
    f16* A_l   = ah((size_t)NB * NB);
    f16* cf_h  = ah((size_t)NB * ND2);
    f16* cf_l  = ah((size_t)NB * ND2);
    f16* zw_h  = ah((size_t)NB * ND2);
    f16* zw_l  = ah((size_t)NB * ND2);
    f16* W1_h  = ah((size_t)ND2 * ND2);
    f16* W1_l  = ah((size_t)ND2 * ND2);
    f16* WqT_h = ah((size_t)ND2 * ND2);
    f16* WqT_l = ah((size_t)ND2 * ND2);
    f16* WkT_h = ah((size_t)ND2 * ND2);
    f16* WkT_l = ah((size_t)ND2 * ND2);
    f16* Bc_h  = ah((size_t)2 * ND2 * ND2);
    f16* Bc_l  = ah((size_t)2 * ND2 * ND2);
    f16* cb_h  = ah((size_t)NK * ND2);
    f16* cb_l  = ah((size_t)NK * ND2);
    f16* dW_h  = ah((size_t)NV * ND2);

    hipMemsetAsync(zw, 0, (size_t)NB * ND2 * sizeof(float), stream);
    k_setup<<<25604, 256, 0, stream>>>(input_ids, emb_mag, emb_phase,
        lin_r, lin_i, q_r, q_i, k_r, k_i, v_r, v_i, codebook, adjacency, dec_W,
        W1_h, W1_l, WqT_h, WqT_l, WkT_h, WkT_l,
        Bc_h + (size_t)ND2 * ND2, Bc_l + (size_t)ND2 * ND2,
        cb_h, cb_l, dW_h, z_h, z_l, cbn, lse, ptrb, remainb, scal, amin2);
    // M' GEMM writes split Bc rows directly via EPI2 sec0 (N=1024 -> all sec0)
    k_sgemm9<2><<<dim3(16, 16), 512, 0, stream>>>(WkT_h, WkT_l, WqT_h, WqT_l, nullptr,
        Bc_h, Bc_l, nullptr, nullptr, ND2, ND2, 1.f, nullptr, nullptr);
    k_sgemm9<0><<<dim3(16, 16), 512, 0, stream>>>(cb_h, cb_l, W1_h, W1_l, CW1,
        nullptr, nullptr, nullptr, nullptr, ND2, ND2, 1.f, nullptr, nullptr);
    k_cnorm<<<NK, 256, 0, stream>>>(CW1, nullptr, nullptr, Pn_h, Pn_l,
                                    norm_scale, norm_shift, mod_bias);
    k_sgemm9<2><<<dim3(32, 16), 512, 0, stream>>>(Pn_h, Pn_l, Bc_h, Bc_l, nullptr,
        t_h, t_l, VTt_h, VTt_l, 2 * ND2, ND2, 1.f, nullptr, nullptr);
    k_sgemm9<0><<<dim3(16, 16), 512, 0, stream>>>(t_h, t_l, Pn_h, Pn_l, SS,
        nullptr, nullptr, nullptr, nullptr, NK, ND2, 1.f, nullptr, nullptr);

    for (int step = 0; step < NSTEPS; ++step) {
        if (step == 0) {
            k_sgemm9<0><<<dim3(16, 16), 512, 0, stream>>>(z_h, z_l, W1_h, W1_l, scr,
                nullptr, nullptr, nullptr, nullptr, ND2, ND2, 1.f, nullptr, nullptr);
            k_cnorm<<<NB, 256, 0, stream>>>(scr, nullptr, nullptr, p_h, p_l,
                                            norm_scale, norm_shift, mod_bias);
            k_sgemm9<2><<<dim3(32, 16), 512, 0, stream>>>(p_h, p_l, Bc_h, Bc_l, nullptr,
                t_h, t_l, vT_h, vT_l, 2 * ND2, ND2, 1.f, nullptr, nullptr);
            k_sgemm9<0><<<dim3(16, 16), 512, 0, stream>>>(t_h, t_l, p_h, p_l, scr,
                nullptr, nullptr, nullptr, nullptr, NB, ND2, ATT_SCALE, nullptr, nullptr);
            k_softmax<<<NB, 256, 0, stream>>>(scr, A_h, A_l);
        }
        k_sgemm9<0><<<dim3(16, 16), 512, 0, stream>>>(A_h, A_l, vT_h, vT_l,
            zfh + (size_t)step * NB * ND2,
            nullptr, nullptr, nullptr, nullptr, ND2, NB, 9.765625e-4f, nullptr, nullptr);
        k_stack2<<<NB, 256, 0, stream>>>(zfh, step, halt_W, halt_b, ctrl_W, ctrl_b,
                                         ptrb, Ptab, haltb, cfn, cf_h, cf_l);
        k_sgemm9<3><<<dim3(16, 16), 512, 0, stream>>>(cf_h, cf_l, cb_h, cb_l, nullptr,
            nullptr, nullptr, nullptr, nullptr, NK, ND2, 1.f, cbn,
            amin2 + (size_t)(step & 1) * NB);
        int islast = (step == NSTEPS - 1) ? 1 : 0;
        int grid = islast ? NB : 3 * NB;
        k_vqatt<<<grid, 256, 0, stream>>>(amin2 + (size_t)(step & 1) * NB,
                                          amin2 + (size_t)((step + 1) & 1) * NB,
                                          SS, VTt_h, VTt_l, A_h, A_l, vT_h, vT_l,
                                          codebook, cfn, adjacency, lse, haltb, remainb,
                                          zw, zw_h, zw_l, prev, scal, step, islast);
    }
    k_dgemm7<<<1000, 512, 0, stream>>>(zw_h, dW_h, out, dec_b);
    k_aux<<<1, 1, 0, stream>>>(scal, out + (size_t)NB * NV);
}